// Round 5
// baseline (196.084 us; speedup 1.0000x reference)
//
#include <hip/hip_runtime.h>

typedef __attribute__((ext_vector_type(8))) short short8;
typedef __attribute__((ext_vector_type(4))) float f32x4;
typedef __attribute__((ext_vector_type(16))) float f32x16;

__device__ __forceinline__ unsigned short f2bf(float f) {
    unsigned u = __builtin_bit_cast(unsigned, f);
    u += 0x7FFFu + ((u >> 16) & 1u);
    return (unsigned short)(u >> 16);
}
__device__ __forceinline__ float bf2f(unsigned short b) {
    unsigned u = ((unsigned)b) << 16;
    return __builtin_bit_cast(float, u);
}
__device__ __forceinline__ short8 ld_frag(const uint4* p, size_t idx16) {
    return __builtin_bit_cast(short8, p[idx16]);
}
__device__ __forceinline__ unsigned cvt_pk_bf16(float lo, float hi) {
    unsigned r;
    asm("v_cvt_pk_bf16_f32 %0, %1, %2" : "=v"(r) : "v"(lo), "v"(hi));
    return r;
}
// async global->LDS, 16B per lane; lds base must be wave-uniform (HW adds lane*16)
__device__ __forceinline__ void gload_lds16(const void* g, void* l) {
    __builtin_amdgcn_global_load_lds((const __attribute__((address_space(1))) void*)g,
                                     (__attribute__((address_space(3))) void*)l, 16, 0, 0);
}

// ---------------- RoPE table: cos/sin [2048][32] fp32 ----------------
__global__ void rope_table_kernel(float* cosT, float* sinT) {
    int idx = blockIdx.x * 256 + threadIdx.x;
    int s = idx >> 5, i = idx & 31;
    float inv = powf(10000.f, -(float)i / 32.f);
    float ang = (float)s * inv;
    cosT[idx] = cosf(ang);
    sinT[idx] = sinf(ang);
}

// ---------------- cast x (fp32) -> bf16 ----------------
__global__ void cast_x_kernel(const float* __restrict__ x, unsigned short* __restrict__ xb) {
    int i = blockIdx.x * 256 + threadIdx.x;
    float4 v = reinterpret_cast<const float4*>(x)[i];
    ushort4 o;
    o.x = f2bf(v.x); o.y = f2bf(v.y); o.z = f2bf(v.z); o.w = f2bf(v.w);
    reinterpret_cast<ushort4*>(xb)[i] = o;
}

// ---------------- transpose + cast: in [R][C] fp32 -> out [C][R] bf16 ----------------
__global__ void transpose_cast_kernel(const float* __restrict__ in, unsigned short* __restrict__ out,
                                      int R, int C) {
    __shared__ float t[32][33];
    int c0 = blockIdx.x * 32, r0 = blockIdx.y * 32;
    int tx = threadIdx.x, ty = threadIdx.y;       // 32 x 8
    for (int i = 0; i < 4; ++i)
        t[ty + i * 8][tx] = in[(size_t)(r0 + ty + i * 8) * C + c0 + tx];
    __syncthreads();
    for (int i = 0; i < 4; ++i)
        out[(size_t)(c0 + ty + i * 8) * R + r0 + tx] = f2bf(t[tx][ty + i * 8]);
}

// ---------------- bf16 GEMM: A[M][K] x Bt[N][K]^T -> C ----------------
template <bool OUT_BF16, int NF>
__global__ __launch_bounds__(256) void gemm_bt_kernel(const unsigned short* __restrict__ A,
                                                      const unsigned short* __restrict__ Bt,
                                                      void* __restrict__ Cout,
                                                      int M, int N, int K) {
    constexpr int BN = NF * 32;
    __shared__ __align__(16) unsigned short As[128 * 32];
    __shared__ __align__(16) unsigned short Bs[BN * 32];
    int tid = threadIdx.x;
    int lane = tid & 63;
    int w = tid >> 6;
    int wm = w >> 1, wn = w & 1;
    int m0 = blockIdx.y * 128, n0 = blockIdx.x * BN;
    int rq = lane >> 4, cl = lane & 15;

    f32x4 acc[4][NF] = {};
    const uint4* As4 = reinterpret_cast<const uint4*>(As);
    const uint4* Bs4 = reinterpret_cast<const uint4*>(Bs);

    for (int k0 = 0; k0 < K; k0 += 32) {
        __syncthreads();
        #pragma unroll
        for (int i = 0; i < 2; ++i) {
            int c = i * 256 + tid;
            int r = c >> 2, cc = c & 3;
            gload_lds16(A + (size_t)(m0 + r) * K + k0 + cc * 8,
                        (char*)As + (size_t)(i * 256 + w * 64) * 16);
        }
        #pragma unroll
        for (int i = 0; i < NF / 2; ++i) {
            int c = i * 256 + tid;
            int r = c >> 2, cc = c & 3;
            gload_lds16(Bt + (size_t)(n0 + r) * K + k0 + cc * 8,
                        (char*)Bs + (size_t)(i * 256 + w * 64) * 16);
        }
        __syncthreads();
        short8 af[4], bfr[NF];
        #pragma unroll
        for (int mf = 0; mf < 4; ++mf) {
            int row = wm * 64 + mf * 16 + cl;
            af[mf] = ld_frag(As4, row * 4 + rq);
        }
        #pragma unroll
        for (int nf = 0; nf < NF; ++nf) {
            int row = wn * (NF * 16) + nf * 16 + cl;
            bfr[nf] = ld_frag(Bs4, row * 4 + rq);
        }
        __builtin_amdgcn_s_setprio(1);
        #pragma unroll
        for (int mf = 0; mf < 4; ++mf)
            #pragma unroll
            for (int nf = 0; nf < NF; ++nf)
                acc[mf][nf] = __builtin_amdgcn_mfma_f32_16x16x32_bf16(af[mf], bfr[nf], acc[mf][nf], 0, 0, 0);
        __builtin_amdgcn_s_setprio(0);
    }
    #pragma unroll
    for (int mf = 0; mf < 4; ++mf)
        #pragma unroll
        for (int nf = 0; nf < NF; ++nf)
            #pragma unroll
            for (int r = 0; r < 4; ++r) {
                size_t row = m0 + wm * 64 + mf * 16 + rq * 4 + r;
                size_t col = n0 + wn * (NF * 16) + nf * 16 + cl;
                float v = acc[mf][nf][r];
                if (OUT_BF16)
                    ((unsigned short*)Cout)[row * N + col] = f2bf(v);
                else
                    ((float*)Cout)[row * N + col] = v;
            }
}

// ---------------- RoPE + split: Q scaled by 0.125*log2(e) ----------------
__global__ void rope_split_kernel(const unsigned short* __restrict__ qkv,
                                  const float* __restrict__ cosT, const float* __restrict__ sinT,
                                  unsigned short* __restrict__ Qb, unsigned short* __restrict__ Kb) {
    const float QSCALE = 0.125f * 1.44269504088896f;
    int t = blockIdx.x * 256 + threadIdx.x;
    int d = t & 63;
    int h = (t >> 6) & 15;
    int s = (t >> 10) & 2047;
    int b = t >> 21;
    size_t rowb = ((size_t)(b * 2048 + s)) * 3072;
    int col = h * 64 + d;
    int f = d & 31;
    float cs = cosT[s * 32 + f], sn = sinT[s * 32 + f];
    int d2 = (d < 32) ? d + 32 : d - 32;

    float q  = bf2f(qkv[rowb + col]);
    float qp = bf2f(qkv[rowb + h * 64 + d2]);
    float qo = (d < 32) ? q * cs - qp * sn : q * cs + qp * sn;
    float k  = bf2f(qkv[rowb + 1024 + col]);
    float kp = bf2f(qkv[rowb + 1024 + h * 64 + d2]);
    float ko = (d < 32) ? k * cs - kp * sn : k * cs + kp * sn;

    size_t ho = (size_t)(b * 16 + h);
    Qb[(ho * 2048 + s) * 64 + d] = f2bf(qo * QSCALE);
    Kb[(ho * 2048 + s) * 64 + d] = f2bf(ko);
}

// ---------------- V transpose: qkv v-part -> VT [b,h][64 d][2048 s] ----------------
__global__ void v_transpose_kernel(const unsigned short* __restrict__ qkv,
                                   unsigned short* __restrict__ VT) {
    __shared__ unsigned short t[64][65];
    int s0 = blockIdx.x * 64;
    int h = blockIdx.y, bb = blockIdx.z;
    int tx = threadIdx.x, ty = threadIdx.y;       // 64 x 4
    #pragma unroll
    for (int i = 0; i < 16; ++i) {
        int r = ty + i * 4;
        t[r][tx] = qkv[((size_t)(bb * 2048 + s0 + r)) * 3072 + 2048 + h * 64 + tx];
    }
    __syncthreads();
    size_t ho = (size_t)(bb * 16 + h);
    #pragma unroll
    for (int i = 0; i < 16; ++i) {
        int d = ty + i * 4;
        VT[(ho * 64 + d) * 2048 + s0 + tx] = t[tx][d];
    }
}

// ---------------- flash attention v5: KV-split x2, in-block merge ----------------
// Block = 64 q-rows x 2 kv-halves. Wave w: q-group (w&1), kv-half (w>>1).
// 1024 blocks -> 4 blocks/CU -> 4 waves/SIMD (2x latency hiding vs v4).
__global__ __launch_bounds__(256, 4) void flash_attn_kernel(const unsigned short* __restrict__ Qb,
                                                            const unsigned short* __restrict__ Kb,
                                                            const unsigned short* __restrict__ VT,
                                                            unsigned short* __restrict__ Oattn) {
    const int S = 2048;
    __shared__ float mrg[2][64][34];   // [qgroup][lane][0..31 oacc, 32 m, 33 l]; stride 34 -> 2-way bank (free)
    int tid = threadIdx.x, lane = tid & 63, w = tid >> 6;
    int g = w & 1, kvhalf = w >> 1;
    int gid = blockIdx.x;
    int hh = gid & 31;                 // head id -> fixed XCD (= hh%8): K/V stays in that L2
    int c = 31 - (gid >> 5);           // 64-row q-chunk, heavy first (LPT)
    size_t headOff = (size_t)hh * S * 64;
    const uint4* Kg4 = reinterpret_cast<const uint4*>(Kb + headOff);
    const uint4* Vg4 = reinterpret_cast<const uint4*>(VT + headOff);   // [64][S]
    int l31 = lane & 31, hi = lane >> 5;
    int qw = c * 64 + g * 32;
    int qrow = qw + l31;

    // Q fragments (pre-scaled by 0.125*log2e): Q[qrow][cc*16 + hi*8 + j]
    short8 qf[4];
    {
        const uint4* Qg4 = reinterpret_cast<const uint4*>(Qb + headOff);
        #pragma unroll
        for (int cc = 0; cc < 4; ++cc)
            qf[cc] = ld_frag(Qg4, (size_t)qrow * 8 + cc * 2 + hi);
    }

    f32x16 oacc0 = {}, oacc1 = {};
    float m = -INFINITY, l = 0.f;
    int nk = (qw + 32 + 63) / 64;                  // total 64-kv tiles this q-group needs
    int ktlo = kvhalf ? (nk + 1) / 2 : 0;
    int kthi = kvhalf ? nk : (nk + 1) / 2;

    for (int kt = ktlo; kt < kthi; ++kt) {
        int kv0 = kt * 64;
        // K fragments direct from L2: rows kv0+l31 (k0) and kv0+32+l31 (k1)
        size_t kb0 = ((size_t)(kv0 + l31) * 64) >> 3;
        short8 k0[4], k1[4];
        #pragma unroll
        for (int cc = 0; cc < 4; ++cc) {
            k0[cc] = ld_frag(Kg4, kb0 + cc * 2 + hi);
            k1[cc] = ld_frag(Kg4, kb0 + 256 + cc * 2 + hi);
        }
        // QK^T (swapped): lane holds S^T[kv][qrow], kv = kv0 + {l31, l31+32}
        f32x16 s0 = {}, s1 = {};
        __builtin_amdgcn_s_setprio(1);
        #pragma unroll
        for (int cc = 0; cc < 4; ++cc) {
            s0 = __builtin_amdgcn_mfma_f32_32x32x16_bf16(k0[cc], qf[cc], s0, 0, 0, 0);
            s1 = __builtin_amdgcn_mfma_f32_32x32x16_bf16(k1[cc], qf[cc], s1, 0, 0, 0);
        }
        __builtin_amdgcn_s_setprio(0);
        // V fragments prefetched (used ~400 cyc later, after softmax)
        size_t vb0 = (size_t)l31 * 256 + (kv0 >> 3);
        short8 vf0[4], vf1[4];
        #pragma unroll
        for (int t = 0; t < 4; ++t) {
            vf0[t] = ld_frag(Vg4, vb0 + t * 2 + hi);
            vf1[t] = ld_frag(Vg4, vb0 + 32 * 256 + t * 2 + hi);
        }

        // mask + tile max (tree; scores already in exp2 domain)
        float tmv[4];
        if (kv0 + 63 <= qw) {
            #pragma unroll
            for (int j = 0; j < 4; ++j) {
                float a = fmaxf(fmaxf(s0[j], s0[j + 4]), fmaxf(s0[j + 8], s0[j + 12]));
                float b = fmaxf(fmaxf(s1[j], s1[j + 4]), fmaxf(s1[j + 8], s1[j + 12]));
                tmv[j] = fmaxf(a, b);
            }
        } else {
            #pragma unroll
            for (int r = 0; r < 16; ++r) {
                int kva = kv0 + (r & 3) + 8 * (r >> 2) + 4 * hi;
                s0[r] = (kva <= qrow) ? s0[r] : -INFINITY;
                s1[r] = (kva + 32 <= qrow) ? s1[r] : -INFINITY;
            }
            #pragma unroll
            for (int j = 0; j < 4; ++j) {
                float a = fmaxf(fmaxf(s0[j], s0[j + 4]), fmaxf(s0[j + 8], s0[j + 12]));
                float b = fmaxf(fmaxf(s1[j], s1[j + 4]), fmaxf(s1[j + 8], s1[j + 12]));
                tmv[j] = fmaxf(a, b);
            }
        }
        float tm = fmaxf(fmaxf(tmv[0], tmv[1]), fmaxf(tmv[2], tmv[3]));
        tm = fmaxf(tm, __shfl_xor(tm, 32));
        // defer-max: rescale only when max grew by >8 (P bounded by 2^8)
        if (!__all(tm - m <= 8.f)) {
            float mn = fmaxf(m, tm);
            float al = exp2f(m - mn);
            m = mn;
            l *= al;
            #pragma unroll
            for (int r = 0; r < 16; ++r) { oacc0[r] *= al; oacc1[r] *= al; }
        }
        #pragma unroll
        for (int r = 0; r < 16; ++r) {
            s0[r] = exp2f(s0[r] - m);
            s1[r] = exp2f(s1[r] - m);
        }
        float rp[4];
        #pragma unroll
        for (int j = 0; j < 4; ++j)
            rp[j] = ((s0[j] + s0[j + 4]) + (s0[j + 8] + s0[j + 12])) +
                    ((s1[j] + s1[j + 4]) + (s1[j + 8] + s1[j + 12]));
        float rs = (rp[0] + rp[1]) + (rp[2] + rp[3]);
        rs += __shfl_xor(rs, 32);
        l += rs;

        // P -> bf16 B-fragments: cvt_pk pack + half-wave exchange (8 shfl)
        unsigned wd[16];
        #pragma unroll
        for (int i = 0; i < 8; ++i) {
            wd[i]     = cvt_pk_bf16(s0[2 * i], s0[2 * i + 1]);
            wd[i + 8] = cvt_pk_bf16(s1[2 * i], s1[2 * i + 1]);
        }
        const int m0i[8] = {0, 1, 4, 5, 8, 9, 12, 13};
        const int m1i[8] = {2, 3, 6, 7, 10, 11, 14, 15};
        unsigned r8[8];
        #pragma unroll
        for (int i = 0; i < 8; ++i)
            r8[i] = (unsigned)__shfl_xor((int)(hi ? wd[m0i[i]] : wd[m1i[i]]), 32);
        short8 pb[4];
        #pragma unroll
        for (int j = 0; j < 4; ++j) {
            uint4 lo = {wd[m0i[2 * j]], wd[m0i[2 * j + 1]], r8[2 * j], r8[2 * j + 1]};
            uint4 hv = {r8[2 * j], r8[2 * j + 1], wd[m1i[2 * j]], wd[m1i[2 * j + 1]]};
            pb[j] = __builtin_bit_cast(short8, hi ? hv : lo);
        }

        // PV (swapped): oacc = V^T x P^T   (V already in regs)
        __builtin_amdgcn_s_setprio(1);
        #pragma unroll
        for (int t = 0; t < 4; ++t) {
            oacc0 = __builtin_amdgcn_mfma_f32_32x32x16_bf16(vf0[t], pb[t], oacc0, 0, 0, 0);
            oacc1 = __builtin_amdgcn_mfma_f32_32x32x16_bf16(vf1[t], pb[t], oacc1, 0, 0, 0);
        }
        __builtin_amdgcn_s_setprio(0);
    }

    // ---- in-block merge of the two kv-halves ----
    if (kvhalf) {
        float* dst = &mrg[g][lane][0];
        #pragma unroll
        for (int r = 0; r < 16; ++r) { dst[r] = oacc0[r]; dst[16 + r] = oacc1[r]; }
        dst[32] = m;
        dst[33] = l;
    }
    __syncthreads();
    if (kvhalf) return;

    const float* src = &mrg[g][lane][0];
    float mB = src[32], lB = src[33];
    float M = fmaxf(m, mB);
    float wA = exp2f(m - M), wB = exp2f(mB - M);
    float L = l * wA + lB * wB;
    float invl = 1.f / L;
    float sA = wA * invl, sB = wB * invl;

    size_t orow = ((size_t)((hh >> 4) * 2048 + qrow)) * 1024 + (hh & 15) * 64;
    #pragma unroll
    for (int du = 0; du < 2; ++du) {
        const f32x16& oa = du ? oacc1 : oacc0;
        const float* ob = src + du * 16;
        #pragma unroll
        for (int gq = 0; gq < 4; ++gq) {
            ushort4 o;
            o.x = f2bf(oa[4 * gq + 0] * sA + ob[4 * gq + 0] * sB);
            o.y = f2bf(oa[4 * gq + 1] * sA + ob[4 * gq + 1] * sB);
            o.z = f2bf(oa[4 * gq + 2] * sA + ob[4 * gq + 2] * sB);
            o.w = f2bf(oa[4 * gq + 3] * sA + ob[4 * gq + 3] * sB);
            int d = du * 32 + 4 * hi + 8 * gq;
            *reinterpret_cast<ushort4*>(Oattn + orow + d) = o;
        }
    }
}

extern "C" void kernel_launch(void* const* d_in, const int* in_sizes, int n_in,
                              void* d_out, int out_size, void* d_ws, size_t ws_size,
                              hipStream_t stream) {
    const float* x    = (const float*)d_in[0];   // [2,2048,1024]
    const float* wqkv = (const float*)d_in[1];   // [1024,3072]
    const float* wout = (const float*)d_in[2];   // [1024,1024]

    char* ws = (char*)d_ws;
    unsigned short* xb    = (unsigned short*)(ws);                       // 8 MB
    unsigned short* wqkvT = (unsigned short*)(ws + (8ull  << 20));       // 6 MB
    unsigned short* woutT = (unsigned short*)(ws + (14ull << 20));       // 2 MB
    unsigned short* qkv   = (unsigned short*)(ws + (16ull << 20));       // 24 MB
    unsigned short* Qb    = (unsigned short*)(ws + (40ull << 20));       // 8 MB
    unsigned short* Kb    = (unsigned short*)(ws + (48ull << 20));       // 8 MB
    unsigned short* VT    = (unsigned short*)(ws + (56ull << 20));       // 8 MB
    unsigned short* Oat   = (unsigned short*)(ws + (64ull << 20));       // 8 MB
    float* cosT           = (float*)(ws + (72ull << 20));                // 256 KB
    float* sinT           = (float*)(ws + (72ull << 20) + (256u << 10)); // 256 KB

    rope_table_kernel<<<256, 256, 0, stream>>>(cosT, sinT);
    cast_x_kernel<<<4096, 256, 0, stream>>>(x, xb);
    transpose_cast_kernel<<<dim3(96, 32), dim3(32, 8), 0, stream>>>(wqkv, wqkvT, 1024, 3072);
    transpose_cast_kernel<<<dim3(32, 32), dim3(32, 8), 0, stream>>>(wout, woutT, 1024, 1024);
    gemm_bt_kernel<true, 4><<<dim3(24, 32), 256, 0, stream>>>(xb, wqkvT, qkv, 4096, 3072, 1024);
    rope_split_kernel<<<16384, 256, 0, stream>>>(qkv, cosT, sinT, Qb, Kb);
    v_transpose_kernel<<<dim3(32, 16, 2), dim3(64, 4), 0, stream>>>(qkv, VT);
    flash_attn_kernel<<<1024, 256, 0, stream>>>(Qb, Kb, VT, Oat);
    gemm_bt_kernel<false, 2><<<dim3(16, 32), 256, 0, stream>>>(Oat, woutT, d_out, 4096, 1024, 1024);
}

// Round 6
// 161.282 us; speedup vs baseline: 1.2158x; 1.2158x over previous
//
#include <hip/hip_runtime.h>

typedef __attribute__((ext_vector_type(8))) short short8;
typedef __attribute__((ext_vector_type(4))) float f32x4;
typedef __attribute__((ext_vector_type(16))) float f32x16;

__device__ __forceinline__ unsigned short f2bf(float f) {
    unsigned u = __builtin_bit_cast(unsigned, f);
    u += 0x7FFFu + ((u >> 16) & 1u);
    return (unsigned short)(u >> 16);
}
__device__ __forceinline__ float bf2f(unsigned short b) {
    unsigned u = ((unsigned)b) << 16;
    return __builtin_bit_cast(float, u);
}
__device__ __forceinline__ short8 ld_frag(const uint4* p, size_t idx16) {
    return __builtin_bit_cast(short8, p[idx16]);
}
__device__ __forceinline__ unsigned cvt_pk_bf16(float lo, float hi) {
    unsigned r;
    asm("v_cvt_pk_bf16_f32 %0, %1, %2" : "=v"(r) : "v"(lo), "v"(hi));
    return r;
}
// async global->LDS, 16B per lane; lds base must be wave-uniform (HW adds lane*16)
__device__ __forceinline__ void gload_lds16(const void* g, void* l) {
    __builtin_amdgcn_global_load_lds((const __attribute__((address_space(1))) void*)g,
                                     (__attribute__((address_space(3))) void*)l, 16, 0, 0);
}

// ---------------- RoPE table: cos/sin [2048][32] fp32 ----------------
__global__ void rope_table_kernel(float* cosT, float* sinT) {
    int idx = blockIdx.x * 256 + threadIdx.x;
    int s = idx >> 5, i = idx & 31;
    float inv = powf(10000.f, -(float)i / 32.f);
    float ang = (float)s * inv;
    cosT[idx] = cosf(ang);
    sinT[idx] = sinf(ang);
}

// ---------------- cast x (fp32) -> bf16 ----------------
__global__ void cast_x_kernel(const float* __restrict__ x, unsigned short* __restrict__ xb) {
    int i = blockIdx.x * 256 + threadIdx.x;
    float4 v = reinterpret_cast<const float4*>(x)[i];
    ushort4 o;
    o.x = f2bf(v.x); o.y = f2bf(v.y); o.z = f2bf(v.z); o.w = f2bf(v.w);
    reinterpret_cast<ushort4*>(xb)[i] = o;
}

// ---------------- transpose + cast: in [R][C] fp32 -> out [C][R] bf16 ----------------
__global__ void transpose_cast_kernel(const float* __restrict__ in, unsigned short* __restrict__ out,
                                      int R, int C) {
    __shared__ float t[32][33];
    int c0 = blockIdx.x * 32, r0 = blockIdx.y * 32;
    int tx = threadIdx.x, ty = threadIdx.y;       // 32 x 8
    for (int i = 0; i < 4; ++i)
        t[ty + i * 8][tx] = in[(size_t)(r0 + ty + i * 8) * C + c0 + tx];
    __syncthreads();
    for (int i = 0; i < 4; ++i)
        out[(size_t)(c0 + ty + i * 8) * R + r0 + tx] = f2bf(t[tx][ty + i * 8]);
}

// ---------------- bf16 GEMM: A[M][K] x Bt[N][K]^T -> C ----------------
template <bool OUT_BF16, int NF>
__global__ __launch_bounds__(256) void gemm_bt_kernel(const unsigned short* __restrict__ A,
                                                      const unsigned short* __restrict__ Bt,
                                                      void* __restrict__ Cout,
                                                      int M, int N, int K) {
    constexpr int BN = NF * 32;
    __shared__ __align__(16) unsigned short As[128 * 32];
    __shared__ __align__(16) unsigned short Bs[BN * 32];
    int tid = threadIdx.x;
    int lane = tid & 63;
    int w = tid >> 6;
    int wm = w >> 1, wn = w & 1;
    int m0 = blockIdx.y * 128, n0 = blockIdx.x * BN;
    int rq = lane >> 4, cl = lane & 15;

    f32x4 acc[4][NF] = {};
    const uint4* As4 = reinterpret_cast<const uint4*>(As);
    const uint4* Bs4 = reinterpret_cast<const uint4*>(Bs);

    for (int k0 = 0; k0 < K; k0 += 32) {
        __syncthreads();
        #pragma unroll
        for (int i = 0; i < 2; ++i) {
            int c = i * 256 + tid;
            int r = c >> 2, cc = c & 3;
            gload_lds16(A + (size_t)(m0 + r) * K + k0 + cc * 8,
                        (char*)As + (size_t)(i * 256 + w * 64) * 16);
        }
        #pragma unroll
        for (int i = 0; i < NF / 2; ++i) {
            int c = i * 256 + tid;
            int r = c >> 2, cc = c & 3;
            gload_lds16(Bt + (size_t)(n0 + r) * K + k0 + cc * 8,
                        (char*)Bs + (size_t)(i * 256 + w * 64) * 16);
        }
        __syncthreads();
        short8 af[4], bfr[NF];
        #pragma unroll
        for (int mf = 0; mf < 4; ++mf) {
            int row = wm * 64 + mf * 16 + cl;
            af[mf] = ld_frag(As4, row * 4 + rq);
        }
        #pragma unroll
        for (int nf = 0; nf < NF; ++nf) {
            int row = wn * (NF * 16) + nf * 16 + cl;
            bfr[nf] = ld_frag(Bs4, row * 4 + rq);
        }
        __builtin_amdgcn_s_setprio(1);
        #pragma unroll
        for (int mf = 0; mf < 4; ++mf)
            #pragma unroll
            for (int nf = 0; nf < NF; ++nf)
                acc[mf][nf] = __builtin_amdgcn_mfma_f32_16x16x32_bf16(af[mf], bfr[nf], acc[mf][nf], 0, 0, 0);
        __builtin_amdgcn_s_setprio(0);
    }
    #pragma unroll
    for (int mf = 0; mf < 4; ++mf)
        #pragma unroll
        for (int nf = 0; nf < NF; ++nf)
            #pragma unroll
            for (int r = 0; r < 4; ++r) {
                size_t row = m0 + wm * 64 + mf * 16 + rq * 4 + r;
                size_t col = n0 + wn * (NF * 16) + nf * 16 + cl;
                float v = acc[mf][nf][r];
                if (OUT_BF16)
                    ((unsigned short*)Cout)[row * N + col] = f2bf(v);
                else
                    ((float*)Cout)[row * N + col] = v;
            }
}

// ---------------- RoPE + split: Q scaled by 0.125*log2(e) ----------------
__global__ void rope_split_kernel(const unsigned short* __restrict__ qkv,
                                  const float* __restrict__ cosT, const float* __restrict__ sinT,
                                  unsigned short* __restrict__ Qb, unsigned short* __restrict__ Kb) {
    const float QSCALE = 0.125f * 1.44269504088896f;
    int t = blockIdx.x * 256 + threadIdx.x;
    int d = t & 63;
    int h = (t >> 6) & 15;
    int s = (t >> 10) & 2047;
    int b = t >> 21;
    size_t rowb = ((size_t)(b * 2048 + s)) * 3072;
    int col = h * 64 + d;
    int f = d & 31;
    float cs = cosT[s * 32 + f], sn = sinT[s * 32 + f];
    int d2 = (d < 32) ? d + 32 : d - 32;

    float q  = bf2f(qkv[rowb + col]);
    float qp = bf2f(qkv[rowb + h * 64 + d2]);
    float qo = (d < 32) ? q * cs - qp * sn : q * cs + qp * sn;
    float k  = bf2f(qkv[rowb + 1024 + col]);
    float kp = bf2f(qkv[rowb + 1024 + h * 64 + d2]);
    float ko = (d < 32) ? k * cs - kp * sn : k * cs + kp * sn;

    size_t ho = (size_t)(b * 16 + h);
    Qb[(ho * 2048 + s) * 64 + d] = f2bf(qo * QSCALE);
    Kb[(ho * 2048 + s) * 64 + d] = f2bf(ko);
}

// ---------------- V transpose: qkv v-part -> VT [b,h][64 d][2048 s] ----------------
__global__ void v_transpose_kernel(const unsigned short* __restrict__ qkv,
                                   unsigned short* __restrict__ VT) {
    __shared__ unsigned short t[64][65];
    int s0 = blockIdx.x * 64;
    int h = blockIdx.y, bb = blockIdx.z;
    int tx = threadIdx.x, ty = threadIdx.y;       // 64 x 4
    #pragma unroll
    for (int i = 0; i < 16; ++i) {
        int r = ty + i * 4;
        t[r][tx] = qkv[((size_t)(bb * 2048 + s0 + r)) * 3072 + 2048 + h * 64 + tx];
    }
    __syncthreads();
    size_t ho = (size_t)(bb * 16 + h);
    #pragma unroll
    for (int i = 0; i < 16; ++i) {
        int d = ty + i * 4;
        VT[(ho * 64 + d) * 2048 + s0 + tx] = t[tx][d];
    }
}

// ---------------- flash attention v6: KV-split x2, in-block merge, no VGPR cap ----------------
// Block = 64 q-rows x 2 kv-halves. Wave w: q-group (w&1), kv-half (w>>1).
// launch_bounds(256,2): VGPR cap 256 -> NO spill (v5's (256,4) spilled to scratch: 45MB writes).
__global__ __launch_bounds__(256, 2) void flash_attn_kernel(const unsigned short* __restrict__ Qb,
                                                            const unsigned short* __restrict__ Kb,
                                                            const unsigned short* __restrict__ VT,
                                                            unsigned short* __restrict__ Oattn) {
    const int S = 2048;
    __shared__ float mrg[2][64][34];   // [qgroup][lane][0..31 oacc, 32 m, 33 l]
    int tid = threadIdx.x, lane = tid & 63, w = tid >> 6;
    int g = w & 1, kvhalf = w >> 1;
    int gid = blockIdx.x;
    int hh = gid & 31;                 // head id -> fixed XCD (= hh%8): K/V stays in that L2
    int c = 31 - (gid >> 5);           // 64-row q-chunk, heavy first (LPT)
    size_t headOff = (size_t)hh * S * 64;
    const uint4* Kg4 = reinterpret_cast<const uint4*>(Kb + headOff);
    const uint4* Vg4 = reinterpret_cast<const uint4*>(VT + headOff);   // [64][S]
    int l31 = lane & 31, hi = lane >> 5;
    int qw = c * 64 + g * 32;
    int qrow = qw + l31;

    // Q fragments (pre-scaled by 0.125*log2e): Q[qrow][cc*16 + hi*8 + j]
    short8 qf[4];
    {
        const uint4* Qg4 = reinterpret_cast<const uint4*>(Qb + headOff);
        #pragma unroll
        for (int cc = 0; cc < 4; ++cc)
            qf[cc] = ld_frag(Qg4, (size_t)qrow * 8 + cc * 2 + hi);
    }

    f32x16 oacc0 = {}, oacc1 = {};
    float m = -INFINITY, l = 0.f;
    int nk = (qw + 32 + 63) / 64;                  // total 64-kv tiles this q-group needs
    int ktlo = kvhalf ? (nk + 1) / 2 : 0;
    int kthi = kvhalf ? nk : (nk + 1) / 2;

    for (int kt = ktlo; kt < kthi; ++kt) {
        int kv0 = kt * 64;
        // K fragments direct from L2: rows kv0+l31 (k0) and kv0+32+l31 (k1)
        size_t kb0 = ((size_t)(kv0 + l31) * 64) >> 3;
        short8 k0[4], k1[4];
        #pragma unroll
        for (int cc = 0; cc < 4; ++cc) {
            k0[cc] = ld_frag(Kg4, kb0 + cc * 2 + hi);
            k1[cc] = ld_frag(Kg4, kb0 + 256 + cc * 2 + hi);
        }
        // QK^T (swapped): lane holds S^T[kv][qrow], kv = kv0 + {l31, l31+32}
        f32x16 s0 = {}, s1 = {};
        __builtin_amdgcn_s_setprio(1);
        #pragma unroll
        for (int cc = 0; cc < 4; ++cc) {
            s0 = __builtin_amdgcn_mfma_f32_32x32x16_bf16(k0[cc], qf[cc], s0, 0, 0, 0);
            s1 = __builtin_amdgcn_mfma_f32_32x32x16_bf16(k1[cc], qf[cc], s1, 0, 0, 0);
        }
        __builtin_amdgcn_s_setprio(0);

        // mask + tile max (tree; scores already in exp2 domain)
        float tmv[4];
        if (kv0 + 63 <= qw) {
            #pragma unroll
            for (int j = 0; j < 4; ++j) {
                float a = fmaxf(fmaxf(s0[j], s0[j + 4]), fmaxf(s0[j + 8], s0[j + 12]));
                float b = fmaxf(fmaxf(s1[j], s1[j + 4]), fmaxf(s1[j + 8], s1[j + 12]));
                tmv[j] = fmaxf(a, b);
            }
        } else {
            #pragma unroll
            for (int r = 0; r < 16; ++r) {
                int kva = kv0 + (r & 3) + 8 * (r >> 2) + 4 * hi;
                s0[r] = (kva <= qrow) ? s0[r] : -INFINITY;
                s1[r] = (kva + 32 <= qrow) ? s1[r] : -INFINITY;
            }
            #pragma unroll
            for (int j = 0; j < 4; ++j) {
                float a = fmaxf(fmaxf(s0[j], s0[j + 4]), fmaxf(s0[j + 8], s0[j + 12]));
                float b = fmaxf(fmaxf(s1[j], s1[j + 4]), fmaxf(s1[j + 8], s1[j + 12]));
                tmv[j] = fmaxf(a, b);
            }
        }
        float tm = fmaxf(fmaxf(tmv[0], tmv[1]), fmaxf(tmv[2], tmv[3]));
        tm = fmaxf(tm, __shfl_xor(tm, 32));

        // V fragments issued here (K regs dead; ~400 cyc of softmax to hide L2 latency)
        size_t vb0 = (size_t)l31 * 256 + (kv0 >> 3);
        short8 vf0[4], vf1[4];
        #pragma unroll
        for (int t = 0; t < 4; ++t) {
            vf0[t] = ld_frag(Vg4, vb0 + t * 2 + hi);
            vf1[t] = ld_frag(Vg4, vb0 + 32 * 256 + t * 2 + hi);
        }

        // defer-max: rescale only when max grew by >8 (P bounded by 2^8)
        if (!__all(tm - m <= 8.f)) {
            float mn = fmaxf(m, tm);
            float al = exp2f(m - mn);
            m = mn;
            l *= al;
            #pragma unroll
            for (int r = 0; r < 16; ++r) { oacc0[r] *= al; oacc1[r] *= al; }
        }
        #pragma unroll
        for (int r = 0; r < 16; ++r) {
            s0[r] = exp2f(s0[r] - m);
            s1[r] = exp2f(s1[r] - m);
        }
        float rp[4];
        #pragma unroll
        for (int j = 0; j < 4; ++j)
            rp[j] = ((s0[j] + s0[j + 4]) + (s0[j + 8] + s0[j + 12])) +
                    ((s1[j] + s1[j + 4]) + (s1[j + 8] + s1[j + 12]));
        float rs = (rp[0] + rp[1]) + (rp[2] + rp[3]);
        rs += __shfl_xor(rs, 32);
        l += rs;

        // P -> bf16 B-fragments: cvt_pk pack + half-wave exchange (8 shfl)
        unsigned wd[16];
        #pragma unroll
        for (int i = 0; i < 8; ++i) {
            wd[i]     = cvt_pk_bf16(s0[2 * i], s0[2 * i + 1]);
            wd[i + 8] = cvt_pk_bf16(s1[2 * i], s1[2 * i + 1]);
        }
        const int m0i[8] = {0, 1, 4, 5, 8, 9, 12, 13};
        const int m1i[8] = {2, 3, 6, 7, 10, 11, 14, 15};
        unsigned r8[8];
        #pragma unroll
        for (int i = 0; i < 8; ++i)
            r8[i] = (unsigned)__shfl_xor((int)(hi ? wd[m0i[i]] : wd[m1i[i]]), 32);
        short8 pb[4];
        #pragma unroll
        for (int j = 0; j < 4; ++j) {
            uint4 lo = {wd[m0i[2 * j]], wd[m0i[2 * j + 1]], r8[2 * j], r8[2 * j + 1]};
            uint4 hv = {r8[2 * j], r8[2 * j + 1], wd[m1i[2 * j]], wd[m1i[2 * j + 1]]};
            pb[j] = __builtin_bit_cast(short8, hi ? hv : lo);
        }

        // PV (swapped): oacc = V^T x P^T   (V already in regs)
        __builtin_amdgcn_s_setprio(1);
        #pragma unroll
        for (int t = 0; t < 4; ++t) {
            oacc0 = __builtin_amdgcn_mfma_f32_32x32x16_bf16(vf0[t], pb[t], oacc0, 0, 0, 0);
            oacc1 = __builtin_amdgcn_mfma_f32_32x32x16_bf16(vf1[t], pb[t], oacc1, 0, 0, 0);
        }
        __builtin_amdgcn_s_setprio(0);
    }

    // ---- in-block merge of the two kv-halves ----
    if (kvhalf) {
        float* dst = &mrg[g][lane][0];
        #pragma unroll
        for (int r = 0; r < 16; ++r) { dst[r] = oacc0[r]; dst[16 + r] = oacc1[r]; }
        dst[32] = m;
        dst[33] = l;
    }
    __syncthreads();
    if (kvhalf) return;

    const float* src = &mrg[g][lane][0];
    float mB = src[32], lB = src[33];
    float M = fmaxf(m, mB);
    float wA = exp2f(m - M), wB = exp2f(mB - M);
    float L = l * wA + lB * wB;
    float invl = 1.f / L;
    float sA = wA * invl, sB = wB * invl;

    size_t orow = ((size_t)((hh >> 4) * 2048 + qrow)) * 1024 + (hh & 15) * 64;
    #pragma unroll
    for (int du = 0; du < 2; ++du) {
        const f32x16& oa = du ? oacc1 : oacc0;
        const float* ob = src + du * 16;
        #pragma unroll
        for (int gq = 0; gq < 4; ++gq) {
            ushort4 o;
            o.x = f2bf(oa[4 * gq + 0] * sA + ob[4 * gq + 0] * sB);
            o.y = f2bf(oa[4 * gq + 1] * sA + ob[4 * gq + 1] * sB);
            o.z = f2bf(oa[4 * gq + 2] * sA + ob[4 * gq + 2] * sB);
            o.w = f2bf(oa[4 * gq + 3] * sA + ob[4 * gq + 3] * sB);
            int d = du * 32 + 4 * hi + 8 * gq;
            *reinterpret_cast<ushort4*>(Oattn + orow + d) = o;
        }
    }
}

extern "C" void kernel_launch(void* const* d_in, const int* in_sizes, int n_in,
                              void* d_out, int out_size, void* d_ws, size_t ws_size,
                              hipStream_t stream) {
    const float* x    = (const float*)d_in[0];   // [2,2048,1024]
    const float* wqkv = (const float*)d_in[1];   // [1024,3072]
    const float* wout = (const float*)d_in[2];   // [1024,1024]

    char* ws = (char*)d_ws;
    unsigned short* xb    = (unsigned short*)(ws);                       // 8 MB
    unsigned short* wqkvT = (unsigned short*)(ws + (8ull  << 20));       // 6 MB
    unsigned short* woutT = (unsigned short*)(ws + (14ull << 20));       // 2 MB
    unsigned short* qkv   = (unsigned short*)(ws + (16ull << 20));       // 24 MB
    unsigned short* Qb    = (unsigned short*)(ws + (40ull << 20));       // 8 MB
    unsigned short* Kb    = (unsigned short*)(ws + (48ull << 20));       // 8 MB
    unsigned short* VT    = (unsigned short*)(ws + (56ull << 20));       // 8 MB
    unsigned short* Oat   = (unsigned short*)(ws + (64ull << 20));       // 8 MB
    float* cosT           = (float*)(ws + (72ull << 20));                // 256 KB
    float* sinT           = (float*)(ws + (72ull << 20) + (256u << 10)); // 256 KB

    rope_table_kernel<<<256, 256, 0, stream>>>(cosT, sinT);
    cast_x_kernel<<<4096, 256, 0, stream>>>(x, xb);
    transpose_cast_kernel<<<dim3(96, 32), dim3(32, 8), 0, stream>>>(wqkv, wqkvT, 1024, 3072);
    transpose_cast_kernel<<<dim3(32, 32), dim3(32, 8), 0, stream>>>(wout, woutT, 1024, 1024);
    gemm_bt_kernel<true, 4><<<dim3(24, 32), 256, 0, stream>>>(xb, wqkvT, qkv, 4096, 3072, 1024);
    rope_split_kernel<<<16384, 256, 0, stream>>>(qkv, cosT, sinT, Qb, Kb);
    v_transpose_kernel<<<dim3(32, 16, 2), dim3(64, 4), 0, stream>>>(qkv, VT);
    flash_attn_kernel<<<1024, 256, 0, stream>>>(Qb, Kb, VT, Oat);
    gemm_bt_kernel<false, 2><<<dim3(16, 32), 256, 0, stream>>>(Oat, woutT, d_out, 4096, 1024, 1024);
}